// Round 1
// baseline (47.302 us; speedup 1.0000x reference)
//
#include <hip/hip_runtime.h>

namespace {

constexpr int B = 4;
constexpr int M = 128;
constexpr int ITP = 10;
constexpr int P = M * ITP;          // 1280 interpolated points per batch
constexpr int NPTS = 20000;
constexpr int NQ = B * P;           // 5120 total queries
constexpr int QPW = 8;              // queries handled per wave
constexpr int QG = NQ / QPW;        // 640 query groups
constexpr int NCHUNKS = 8;          // N split per query group -> 5120 waves total
constexpr int CHUNK = (NPTS + NCHUNKS - 1) / NCHUNKS;  // 2500
constexpr int WPB = 4;              // waves per block (256 threads)
constexpr float EPSF = 0.01f;

// t = linspace(0,1,10): nearest-f32 of j/9 (numpy computes in f64 then casts)
__device__ __forceinline__ float t_of(int j) {
  const float T[ITP] = {0.0f,
                        (float)(1.0 / 9.0), (float)(2.0 / 9.0), (float)(3.0 / 9.0),
                        (float)(4.0 / 9.0), (float)(5.0 / 9.0), (float)(6.0 / 9.0),
                        (float)(7.0 / 9.0), (float)(8.0 / 9.0), 1.0f};
  return T[j];
}

// Interpolated cage point, replicating reference rounding:
// x = t*cage_p + (1-t)*cage   (mul, mul, add — no fma contraction)
__device__ __forceinline__ void query_point(const float* __restrict__ cage,
                                            int b, int p,
                                            float& x, float& y, float& z) {
  const int m = p / ITP;
  const int j = p - m * ITP;
  const float t = t_of(j);
  const float omt = __fsub_rn(1.0f, t);
  const float* c0 = cage + ((size_t)b * M + m) * 3;
  const float* c1 = cage + ((size_t)b * M + ((m + 1) & (M - 1))) * 3;
  x = __fadd_rn(__fmul_rn(t, c1[0]), __fmul_rn(omt, c0[0]));
  y = __fadd_rn(__fmul_rn(t, c1[1]), __fmul_rn(omt, c0[1]));
  z = __fadd_rn(__fmul_rn(t, c1[2]), __fmul_rn(omt, c0[2]));
}

// Kernel 1: per (query-group, N-chunk) wave: running argmin over chunk,
// wave-reduce, write packed partial (d2bits<<32 | idx) to workspace.
__global__ __launch_bounds__(256) void k_nn_partial(
    const float* __restrict__ cage,
    const float* __restrict__ shape,
    unsigned long long* __restrict__ part) {
  const int lane = threadIdx.x & 63;
  const int wid  = threadIdx.x >> 6;
  const int qg   = blockIdx.x * WPB + wid;   // 0..QG-1
  const int ck   = blockIdx.y;               // 0..NCHUNKS-1
  const int q0   = qg * QPW;
  const int b    = q0 / P;
  const int p0   = q0 - b * P;               // 8 queries stay within one batch

  float cx[QPW], cy[QPW], cz[QPW], cc[QPW];
#pragma unroll
  for (int i = 0; i < QPW; ++i) {
    float x, y, z;
    query_point(cage, b, p0 + i, x, y, z);
    cx[i] = x; cy[i] = y; cz[i] = z;
    // sum(c*c) in reference order: (x*x + y*y) + z*z
    cc[i] = __fadd_rn(__fadd_rn(__fmul_rn(x, x), __fmul_rn(y, y)), __fmul_rn(z, z));
  }

  float minv[QPW];
  unsigned int mini[QPW];
#pragma unroll
  for (int i = 0; i < QPW; ++i) { minv[i] = __int_as_float(0x7f800000); mini[i] = 0u; }

  const float* sb = shape + (size_t)b * NPTS * 3;
  const int n0 = ck * CHUNK;
  const int n1 = (n0 + CHUNK < NPTS) ? (n0 + CHUNK) : NPTS;
  for (int n = n0 + lane; n < n1; n += 64) {
    const float sx = sb[n * 3 + 0];
    const float sy = sb[n * 3 + 1];
    const float sz = sb[n * 3 + 2];
    const float ss = __fadd_rn(__fadd_rn(__fmul_rn(sx, sx), __fmul_rn(sy, sy)),
                               __fmul_rn(sz, sz));
#pragma unroll
    for (int i = 0; i < QPW; ++i) {
      // d2 = (cc + ss) - 2*dot  — reference's expanded form & grouping
      const float dot = __fmaf_rn(cz[i], sz, __fmaf_rn(cy[i], sy, __fmul_rn(cx[i], sx)));
      const float d2 = __fmaf_rn(-2.0f, dot, __fadd_rn(cc[i], ss));
      if (d2 < minv[i]) { minv[i] = d2; mini[i] = (unsigned int)n; }  // strict < keeps first idx
    }
  }

#pragma unroll
  for (int i = 0; i < QPW; ++i) {
    // monotone total-order transform (robust even if d2 rounds negative)
    unsigned int fb = __float_as_uint(minv[i]);
    fb = (fb & 0x80000000u) ? ~fb : (fb | 0x80000000u);
    unsigned long long pk = ((unsigned long long)fb << 32) | (unsigned long long)mini[i];
#pragma unroll
    for (int s = 32; s >= 1; s >>= 1) {
      const unsigned long long o = __shfl_xor(pk, s, 64);
      pk = (o < pk) ? o : pk;   // equal d2 -> smaller idx wins (first-index tie-break)
    }
    if (lane == i) part[(size_t)(q0 + i) * NCHUNKS + ck] = pk;
  }
}

// Kernel 2: merge chunk partials (index-ordered), compute loss per query,
// deterministic single-block tree reduction -> mean.
__global__ __launch_bounds__(1024) void k_finish(
    const float* __restrict__ cage,
    const float* __restrict__ shape,
    const float* __restrict__ normals,
    const unsigned long long* __restrict__ part,
    float* __restrict__ out) {
  __shared__ float red[1024];
  const int tid = threadIdx.x;
  float acc = 0.0f;
  for (int q = tid; q < NQ; q += 1024) {
    unsigned long long best = ~0ull;
#pragma unroll
    for (int c = 0; c < NCHUNKS; ++c) {
      const unsigned long long v = part[(size_t)q * NCHUNKS + c];
      if (v < best) best = v;   // strict < in ascending chunk order keeps first index
    }
    const int idx = (int)(best & 0xffffffffu);
    const int b = q / P;
    const int p = q - b * P;
    float qx, qy, qz;
    query_point(cage, b, p, qx, qy, qz);
    const float* sp = shape   + ((size_t)b * NPTS + idx) * 3;
    const float* sn = normals + ((size_t)b * NPTS + idx) * 3;
    const float nx = sn[0], ny = sn[1], nz = sn[2];
    // (cage_itp - nn_point - EPS*nn_normal) elementwise, reference order
    const float vx = __fsub_rn(__fsub_rn(qx, sp[0]), __fmul_rn(EPSF, nx));
    const float vy = __fsub_rn(__fsub_rn(qy, sp[1]), __fmul_rn(EPSF, ny));
    const float vz = __fsub_rn(__fsub_rn(qz, sp[2]), __fmul_rn(EPSF, nz));
    const float dot = __fadd_rn(__fadd_rn(__fmul_rn(vx, nx), __fmul_rn(vy, ny)),
                                __fmul_rn(vz, nz));
    acc = __fadd_rn(acc, (dot < 0.0f) ? -dot : 0.0f);
  }
  red[tid] = acc;
  __syncthreads();
  for (int s = 512; s >= 1; s >>= 1) {
    if (tid < s) red[tid] = __fadd_rn(red[tid], red[tid + s]);
    __syncthreads();
  }
  if (tid == 0) out[0] = red[0] / 5120.0f;
}

}  // namespace

extern "C" void kernel_launch(void* const* d_in, const int* in_sizes, int n_in,
                              void* d_out, int out_size, void* d_ws, size_t ws_size,
                              hipStream_t stream) {
  (void)in_sizes; (void)n_in; (void)out_size; (void)ws_size;
  const float* cage    = (const float*)d_in[0];
  const float* shape   = (const float*)d_in[1];
  const float* normals = (const float*)d_in[2];
  float* out = (float*)d_out;
  unsigned long long* part = (unsigned long long*)d_ws;  // NQ*NCHUNKS u64 = 320 KB

  dim3 grid1(QG / WPB, NCHUNKS);   // 160 x 8 blocks, 4 waves each -> 5120 waves
  k_nn_partial<<<grid1, 256, 0, stream>>>(cage, shape, part);
  k_finish<<<1, 1024, 0, stream>>>(cage, shape, normals, part, out);
}

// Round 2
// 36.139 us; speedup vs baseline: 1.3089x; 1.3089x over previous
//
#include <hip/hip_runtime.h>

namespace {

constexpr int B = 4;
constexpr int M = 128;
constexpr int ITP = 10;
constexpr int P = M * ITP;          // 1280 interpolated points per batch
constexpr int NPTS = 20000;
constexpr int NQ = B * P;           // 5120 total queries
constexpr int QPW = 8;              // queries handled per wave
constexpr int QG = NQ / QPW;        // 640 query groups
constexpr int NCHUNKS = 8;          // N split per query group
constexpr int CHUNK = NPTS / NCHUNKS;              // 2500 exactly
constexpr int ITERS = (CHUNK + 63) / 64;           // 40
constexpr int TAIL = CHUNK - (ITERS - 1) * 64;     // 4 valid lanes in last iter
constexpr int WPB = 4;              // waves per block (256 threads)
constexpr float EPSF = 0.01f;

// t = linspace(0,1,10): nearest-f32 of j/9 (numpy computes in f64 then casts)
__device__ const float T_TAB[ITP] = {0.0f,
    (float)(1.0 / 9.0), (float)(2.0 / 9.0), (float)(3.0 / 9.0),
    (float)(4.0 / 9.0), (float)(5.0 / 9.0), (float)(6.0 / 9.0),
    (float)(7.0 / 9.0), (float)(8.0 / 9.0), 1.0f};

// Interpolated cage point, replicating reference rounding:
// x = t*cage_p + (1-t)*cage   (mul, mul, add — no fma contraction)
__device__ __forceinline__ void query_point(const float* __restrict__ cage,
                                            int b, int p,
                                            float& x, float& y, float& z) {
  const int m = p / ITP;
  const int j = p - m * ITP;
  const float t = T_TAB[j];
  const float omt = __fsub_rn(1.0f, t);
  const float* c0 = cage + ((size_t)b * M + m) * 3;
  const float* c1 = cage + ((size_t)b * M + ((m + 1) & (M - 1))) * 3;
  x = __fadd_rn(__fmul_rn(t, c1[0]), __fmul_rn(omt, c0[0]));
  y = __fadd_rn(__fmul_rn(t, c1[1]), __fmul_rn(omt, c0[1]));
  z = __fadd_rn(__fmul_rn(t, c1[2]), __fmul_rn(omt, c0[2]));
}

// One point vs 8 queries: exact reference formula d2 = (cc+ss) - 2*dot.
__device__ __forceinline__ void update8(const float px, const float py,
                                        const float pz, const float ss,
                                        const int n,
                                        const float* __restrict__ cx,
                                        const float* __restrict__ cy,
                                        const float* __restrict__ cz,
                                        const float* __restrict__ cc,
                                        float* __restrict__ minv,
                                        unsigned int* __restrict__ mini) {
#pragma unroll
  for (int i = 0; i < QPW; ++i) {
    const float dot = __fmaf_rn(cz[i], pz, __fmaf_rn(cy[i], py, __fmul_rn(cx[i], px)));
    const float d2 = __fmaf_rn(-2.0f, dot, __fadd_rn(cc[i], ss));
    if (d2 < minv[i]) { minv[i] = d2; mini[i] = (unsigned int)n; }  // strict <: first idx wins
  }
}

// Kernel 1: per (query-group, N-chunk) wave: software-pipelined argmin scan,
// u64 wave-reduce, packed partial (d2bits<<32 | idx) to workspace.
__global__ __launch_bounds__(256) void k_nn_partial(
    const float* __restrict__ cage,
    const float* __restrict__ shape,
    unsigned long long* __restrict__ part) {
  const int lane = threadIdx.x & 63;
  const int wid  = threadIdx.x >> 6;
  const int qg   = blockIdx.x * WPB + wid;   // 0..QG-1
  const int ck   = blockIdx.y;               // 0..NCHUNKS-1
  const int q0   = qg * QPW;
  const int b    = q0 / P;
  const int p0   = q0 - b * P;               // 8 queries stay within one batch

  float cx[QPW], cy[QPW], cz[QPW], cc[QPW];
#pragma unroll
  for (int i = 0; i < QPW; ++i) {
    float x, y, z;
    query_point(cage, b, p0 + i, x, y, z);
    cx[i] = x; cy[i] = y; cz[i] = z;
    cc[i] = __fadd_rn(__fadd_rn(__fmul_rn(x, x), __fmul_rn(y, y)), __fmul_rn(z, z));
  }

  float minv[QPW];
  unsigned int mini[QPW];
#pragma unroll
  for (int i = 0; i < QPW; ++i) { minv[i] = __int_as_float(0x7f800000); mini[i] = 0u; }

  const float* sb = shape + (size_t)b * NPTS * 3;
  const int n0 = ck * CHUNK;

  // --- software-pipelined scan: prefetch it+1 before computing it ---
  int n = n0 + lane;
  const float* pp = sb + (size_t)n * 3;
  float px = pp[0], py = pp[1], pz = pp[2];   // it=0: all lanes valid (64 <= 2500)

  // main: it in [0, ITERS-2); prefetch of it+1 always fully valid
#pragma unroll 4
  for (int it = 0; it < ITERS - 2; ++it) {
    const float* q = sb + (size_t)(n + 64) * 3;
    const float fx = q[0], fy = q[1], fz = q[2];
    const float ss = __fadd_rn(__fadd_rn(__fmul_rn(px, px), __fmul_rn(py, py)),
                               __fmul_rn(pz, pz));
    update8(px, py, pz, ss, n, cx, cy, cz, cc, minv, mini);
    px = fx; py = fy; pz = fz; n += 64;
  }
  {  // it = ITERS-2: prefetch for tail iter (clamp OOB lanes to a safe addr)
    const int na = (lane < TAIL) ? (n + 64) : (n0 + lane);
    const float* q = sb + (size_t)na * 3;
    const float fx = q[0], fy = q[1], fz = q[2];
    const float ss = __fadd_rn(__fadd_rn(__fmul_rn(px, px), __fmul_rn(py, py)),
                               __fmul_rn(pz, pz));
    update8(px, py, pz, ss, n, cx, cy, cz, cc, minv, mini);
    px = fx; py = fy; pz = fz; n += 64;
  }
  {  // it = ITERS-1: only lanes < TAIL valid; mask via ss=+inf (d2=+inf, never wins)
    float ss = __fadd_rn(__fadd_rn(__fmul_rn(px, px), __fmul_rn(py, py)),
                         __fmul_rn(pz, pz));
    if (lane >= TAIL) ss = __int_as_float(0x7f800000);
    update8(px, py, pz, ss, n, cx, cy, cz, cc, minv, mini);
  }

#pragma unroll
  for (int i = 0; i < QPW; ++i) {
    // monotone total-order transform; pack (d2bits, idx) -> u64; min = argmin w/ first-idx ties
    unsigned int fb = __float_as_uint(minv[i]);
    fb = (fb & 0x80000000u) ? ~fb : (fb | 0x80000000u);
    unsigned long long pk = ((unsigned long long)fb << 32) | (unsigned long long)mini[i];
#pragma unroll
    for (int s = 32; s >= 1; s >>= 1) {
      const unsigned long long o = __shfl_xor(pk, s, 64);
      pk = (o < pk) ? o : pk;
    }
    if (lane == i) part[(size_t)(q0 + i) * NCHUNKS + ck] = pk;
  }
}

// Kernel 2a: one thread per query: merge chunk partials (index-ordered),
// compute loss term, block tree-reduce -> per-block sum (deterministic).
__global__ __launch_bounds__(256) void k_loss(
    const float* __restrict__ cage,
    const float* __restrict__ shape,
    const float* __restrict__ normals,
    const unsigned long long* __restrict__ part,
    float* __restrict__ blocksum) {
  const int tid = threadIdx.x;
  const int q = blockIdx.x * 256 + tid;   // NQ = 20 blocks * 256

  unsigned long long best = ~0ull;
#pragma unroll
  for (int c = 0; c < NCHUNKS; ++c) {
    const unsigned long long v = part[(size_t)q * NCHUNKS + c];
    if (v < best) best = v;   // strict < in ascending chunk order keeps first index
  }
  const int idx = (int)(best & 0xffffffffu);
  const int b = q / P;
  const int p = q - b * P;
  float qx, qy, qz;
  query_point(cage, b, p, qx, qy, qz);
  const float* sp = shape   + ((size_t)b * NPTS + idx) * 3;
  const float* sn = normals + ((size_t)b * NPTS + idx) * 3;
  const float nx = sn[0], ny = sn[1], nz = sn[2];
  const float vx = __fsub_rn(__fsub_rn(qx, sp[0]), __fmul_rn(EPSF, nx));
  const float vy = __fsub_rn(__fsub_rn(qy, sp[1]), __fmul_rn(EPSF, ny));
  const float vz = __fsub_rn(__fsub_rn(qz, sp[2]), __fmul_rn(EPSF, nz));
  const float dot = __fadd_rn(__fadd_rn(__fmul_rn(vx, nx), __fmul_rn(vy, ny)),
                              __fmul_rn(vz, nz));
  const float loss = (dot < 0.0f) ? -dot : 0.0f;

  __shared__ float red[256];
  red[tid] = loss;
  __syncthreads();
#pragma unroll
  for (int s = 128; s >= 1; s >>= 1) {
    if (tid < s) red[tid] = __fadd_rn(red[tid], red[tid + s]);
    __syncthreads();
  }
  if (tid == 0) blocksum[blockIdx.x] = red[0];
}

// Kernel 2b: sum the 20 block partials (single wave, fixed butterfly order).
__global__ __launch_bounds__(64) void k_sum(const float* __restrict__ blocksum,
                                            float* __restrict__ out) {
  const int lane = threadIdx.x;
  float v = (lane < NQ / 256) ? blocksum[lane] : 0.0f;
#pragma unroll
  for (int s = 32; s >= 1; s >>= 1) v = __fadd_rn(v, __shfl_xor(v, s, 64));
  if (lane == 0) out[0] = v / (float)NQ;
}

}  // namespace

extern "C" void kernel_launch(void* const* d_in, const int* in_sizes, int n_in,
                              void* d_out, int out_size, void* d_ws, size_t ws_size,
                              hipStream_t stream) {
  (void)in_sizes; (void)n_in; (void)out_size; (void)ws_size;
  const float* cage    = (const float*)d_in[0];
  const float* shape   = (const float*)d_in[1];
  const float* normals = (const float*)d_in[2];
  float* out = (float*)d_out;

  unsigned long long* part = (unsigned long long*)d_ws;          // NQ*NCHUNKS u64 = 320 KB
  float* blocksum = (float*)((char*)d_ws + (size_t)NQ * NCHUNKS * 8);  // 20 floats

  dim3 grid1(QG / WPB, NCHUNKS);   // 160 x 8 blocks, 4 waves each
  k_nn_partial<<<grid1, 256, 0, stream>>>(cage, shape, part);
  k_loss<<<NQ / 256, 256, 0, stream>>>(cage, shape, normals, part, blocksum);
  k_sum<<<1, 64, 0, stream>>>(blocksum, out);
}